// Round 4
// baseline (631.825 us; speedup 1.0000x reference)
//
#include <hip/hip_runtime.h>
#include <stdint.h>

#define HH 2048
#define BB 16384
#define BK 128            // K bytes per main-loop step
#define NK (HH / BK)      // 16

typedef int v4i __attribute__((ext_vector_type(4)));

__device__ __forceinline__ int clip127(int v){
  v = v > 127 ? 127 : v;
  return v < -127 ? -127 : v;
}
// floor division by 720 (matches Python //)
__device__ __forceinline__ int fdiv720(int r){
  int q = r / 720;
  return q - ((r - q * 720) < 0 ? 1 : 0);
}

// Pack int32 (values in [-127,127]) -> int8. 16 elems / thread / iter.
__global__ void pack_i32_to_i8(const int* __restrict__ src, int8_t* __restrict__ dst, int n16){
  int stride = gridDim.x * blockDim.x;
  for (int i = blockIdx.x * blockDim.x + threadIdx.x; i < n16; i += stride){
    const int4* s = (const int4*)src + (size_t)i * 4;
    int4 a = s[0], b = s[1], c = s[2], d = s[3];
    int4 o;
    o.x = (a.x & 255) | ((a.y & 255) << 8) | ((a.z & 255) << 16) | (a.w << 24);
    o.y = (b.x & 255) | ((b.y & 255) << 8) | ((b.z & 255) << 16) | (b.w << 24);
    o.z = (c.x & 255) | ((c.y & 255) << 8) | ((c.z & 255) << 16) | (c.w << 24);
    o.w = (d.x & 255) | ((d.y & 255) << 8) | ((d.z & 255) << 16) | (d.w << 24);
    ((int4*)dst)[i] = o;
  }
}

// Duplicate first half of d_out into second half (int4).
__global__ void dup_out(const int* __restrict__ src, int* __restrict__ dst, int n4){
  int stride = gridDim.x * blockDim.x;
  for (int i = blockIdx.x * blockDim.x + threadIdx.x; i < n4; i += stride)
    ((int4*)dst)[i] = ((const int4*)src)[i];
}

// Single GEMM, 256x256 tile, BK=128 bytes, 8 waves (2x4), double-buffered LDS
// with 2-phase prefetch, XCD-aware block swizzle, XOR-swizzled LDS.
// C = A(16384x2048) @ B(2048x2048)^T, i8 MFMA 16x16x64.
// Epilogues (E):
//  0: v3 = clip(acc//720)                 -> out1[idx] (int32)      [x@Wh]
//  1: v1 = clip(acc//720)                 -> io8[idx]  (int8)       [x@Wf]
//  2: v2=clip(acc//720); v1=io8; ft=clip(v1+v2+b); fg=ft+127;
//     io8[idx]=clip((fg*st)>>8); fg8[idx]=fg                        [s@Uf]
//  3: v2=clip(acc//720); v3=out1; h=clip(v3+v2+b); fg=fg8; st=s8;
//     out1[idx]=clip(st+((fg*(h-st))>>8))                           [g@Uh]
template<int E>
__global__ __launch_bounds__(512, 2)
void gemm256(const int8_t* __restrict__ A, const int8_t* __restrict__ B,
             const int* __restrict__ bias, const int8_t* __restrict__ s8,
             int8_t* io8, uint8_t* fg8, int* out1)
{
  __shared__ __align__(16) int8_t lds[2 * 65536];   // 128 KiB (2 x (A 32K + B 32K))
  const int tid  = threadIdx.x;
  const int lane = tid & 63;
  const int wave = tid >> 6;        // 0..7
  const int wr   = wave >> 2;       // 0..1  (row half)
  const int wc   = wave & 3;        // 0..3  (col quarter)

  // XCD-aware bijective swizzle: 512 blocks, 8 XCDs, 64 per chunk.
  // Co-resident blocks on one XCD get consecutive work -> shared A panels in L2.
  const int bid = blockIdx.x;
  const int wg  = (bid & 7) * 64 + (bid >> 3);
  const int rowbase = (wg >> 3) * 256;   // 64 row tiles
  const int colbase = (wg & 7) * 256;    // 8 col tiles

  const int srow = tid >> 3;   // staging row within 64-row pass
  const int sc   = tid & 7;    // staging 16B chunk slot (of 8 per 128B row)
  const int rl   = lane & 15;
  const int ch   = lane >> 4;  // 0..3: 16B chunk within 64B MFMA k-slice

  v4i acc[8][4];
  const v4i vz = {0,0,0,0};
#pragma unroll
  for (int m = 0; m < 8; m++)
#pragma unroll
    for (int n = 0; n < 4; n++) acc[m][n] = vz;

  // stage one BK-slice of A and B tiles into buffer `buf`
  auto STAGE = [&](int buf, int kk){
    const int k0 = kk * BK;
    const int base = buf * 65536;
#pragma unroll
    for (int p = 0; p < 4; p++){
      const int row = p * 64 + srow;
      const int scx = sc ^ (row & 7);        // inverse swizzle on global source
      __builtin_amdgcn_global_load_lds(
        (const __attribute__((address_space(1))) void*)(A + (size_t)(rowbase + row) * HH + k0 + scx * 16),
        (__attribute__((address_space(3))) void*)(lds + base + p * 8192 + tid * 16), 16, 0, 0);
      __builtin_amdgcn_global_load_lds(
        (const __attribute__((address_space(1))) void*)(B + (size_t)(colbase + row) * HH + k0 + scx * 16),
        (__attribute__((address_space(3))) void*)(lds + base + 32768 + p * 8192 + tid * 16), 16, 0, 0);
    }
  };

  int cur = 0;
  STAGE(0, 0);
  __syncthreads();

  for (int kk = 0; kk < NK; ++kk){
    if (kk + 1 < NK) STAGE(cur ^ 1, kk + 1);   // prefetch next tile (in flight over MFMA)
    const int cb = cur * 65536;
#pragma unroll
    for (int k2 = 0; k2 < 2; ++k2){            // two K=64 slices per BK=128
      v4i af[8], bf[4];
#pragma unroll
      for (int m = 0; m < 8; m++){
        const int row = wr * 128 + m * 16 + rl;
        const int c = (k2 * 4 + ch) ^ (row & 7);
        af[m] = *(const v4i*)(lds + cb + row * BK + c * 16);
      }
#pragma unroll
      for (int n = 0; n < 4; n++){
        const int row = wc * 64 + n * 16 + rl;
        const int c = (k2 * 4 + ch) ^ (row & 7);
        bf[n] = *(const v4i*)(lds + cb + 32768 + row * BK + c * 16);
      }
#pragma unroll
      for (int m = 0; m < 8; m++)
#pragma unroll
        for (int n = 0; n < 4; n++)
          acc[m][n] = __builtin_amdgcn_mfma_i32_16x16x64_i8(af[m], bf[n], acc[m][n], 0, 0, 0);
    }
    __syncthreads();   // drains vmcnt (prefetch done) + lgkm; one barrier per K-step
    cur ^= 1;
  }

  // epilogue: C/D layout col=lane&15, row=(lane>>4)*4+reg
  const int q = lane >> 4;
#pragma unroll
  for (int m = 0; m < 8; m++){
#pragma unroll
    for (int n = 0; n < 4; n++){
      const int gcol = colbase + wc * 64 + n * 16 + rl;
#pragma unroll
      for (int r = 0; r < 4; r++){
        const int grow = rowbase + wr * 128 + m * 16 + q * 4 + r;
        const size_t idx = (size_t)grow * HH + gcol;
        const int v2 = clip127(fdiv720(acc[m][n][r]));
        if (E == 0){
          out1[idx] = v2;
        } else if (E == 1){
          io8[idx] = (int8_t)v2;
        } else if (E == 2){
          const int v1 = io8[idx];
          const int ft = clip127(v1 + v2 + bias[gcol]);
          const int fg = ft + 127;
          const int st = s8[idx];
          io8[idx] = (int8_t)clip127((fg * st) >> 8);   // gated_past (overwrites v1, same thread)
          fg8[idx] = (uint8_t)fg;
        } else {
          const int v3 = out1[idx];
          const int h  = clip127(v3 + v2 + bias[gcol]);
          const int st = s8[idx];
          const int fg = (int)fg8[idx];
          out1[idx] = clip127(st + ((fg * (h - st)) >> 8));  // new_state (same thread r/w)
        }
      }
    }
  }
}

extern "C" void kernel_launch(void* const* d_in, const int* in_sizes, int n_in,
                              void* d_out, int out_size, void* d_ws, size_t ws_size,
                              hipStream_t stream){
  const int* x  = (const int*)d_in[0];
  const int* st = (const int*)d_in[1];
  const int* Wf = (const int*)d_in[2];
  const int* Uf = (const int*)d_in[3];
  const int* bf = (const int*)d_in[4];
  const int* Wh = (const int*)d_in[5];
  const int* Uh = (const int*)d_in[6];
  const int* bh = (const int*)d_in[7];

  const size_t NBH = (size_t)BB * HH;   // 33,554,432 elements
  const size_t NW  = (size_t)HH * HH;   //  4,194,304 elements

  // d_out: int32 x 2*NBH (tuple). First half: v3 (int32) then new_state.
  // Second half (128 MiB) = scratch, fully rewritten by dup_out at the end:
  //   s8 [0,32M) | P [32M,64M): v1 -> gated | F [64M,96M): x8 -> fg8 | weights [96M,112M)
  // Liveness: x8 read only by E0/E1 (before E2 writes fg8 into F). v1 read/
  // overwritten same-thread in E2. No kernel both reads and block-cross-writes
  // any region. d_ws unused.
  int*    out1 = (int*)d_out;
  int8_t* b2   = (int8_t*)d_out + (size_t)NBH * 4;
  int8_t* s8   = b2;
  int8_t* P    = b2 + NBH;
  int8_t* F    = b2 + 2 * NBH;
  int8_t* wh8  = b2 + 3 * NBH;
  int8_t* wf8  = wh8 + NW;
  int8_t* uf8  = wf8 + NW;
  int8_t* uh8  = uf8 + NW;   // ends at 112 MiB

  pack_i32_to_i8<<<2048, 256, 0, stream>>>(x,  F,   (int)(NBH / 16));  // x8
  pack_i32_to_i8<<<2048, 256, 0, stream>>>(st, s8,  (int)(NBH / 16));
  pack_i32_to_i8<<<1024, 256, 0, stream>>>(Wh, wh8, (int)(NW / 16));
  pack_i32_to_i8<<<1024, 256, 0, stream>>>(Wf, wf8, (int)(NW / 16));
  pack_i32_to_i8<<<1024, 256, 0, stream>>>(Uf, uf8, (int)(NW / 16));
  pack_i32_to_i8<<<1024, 256, 0, stream>>>(Uh, uh8, (int)(NW / 16));

  // grid: (16384/256) x (2048/256) = 64 x 8 = 512 blocks, 512 threads
  gemm256<0><<<512, 512, 0, stream>>>(F,  wh8, nullptr, nullptr, nullptr, nullptr, out1);          // v3 = x@Wh
  gemm256<1><<<512, 512, 0, stream>>>(F,  wf8, nullptr, nullptr, P,       nullptr, nullptr);       // v1 = x@Wf
  gemm256<2><<<512, 512, 0, stream>>>(s8, uf8, bf,      s8,      P,       (uint8_t*)F, nullptr);   // gated,fg
  gemm256<3><<<512, 512, 0, stream>>>(P,  uh8, bh,      s8,      nullptr, (uint8_t*)F, out1);      // new_state

  dup_out<<<2048, 256, 0, stream>>>(out1, out1 + NBH, (int)(NBH / 4));
}

// Round 5
// 621.757 us; speedup vs baseline: 1.0162x; 1.0162x over previous
//
#include <hip/hip_runtime.h>
#include <stdint.h>

#define HH 2048
#define BB 16384
#define NK (HH / 64)     // 32 K-steps of 64 bytes

typedef int v4i __attribute__((ext_vector_type(4)));

__device__ __forceinline__ int clip127(int v){
  v = v > 127 ? 127 : v;
  return v < -127 ? -127 : v;
}
// floor division by 720 (matches Python //)
__device__ __forceinline__ int fdiv720(int r){
  int q = r / 720;
  return q - ((r - q * 720) < 0 ? 1 : 0);
}

// Pack int32 (values in [-127,127]) -> int8. 16 elems / thread / iter.
__global__ void pack_i32_to_i8(const int* __restrict__ src, int8_t* __restrict__ dst, int n16){
  int stride = gridDim.x * blockDim.x;
  for (int i = blockIdx.x * blockDim.x + threadIdx.x; i < n16; i += stride){
    const int4* s = (const int4*)src + (size_t)i * 4;
    int4 a = s[0], b = s[1], c = s[2], d = s[3];
    int4 o;
    o.x = (a.x & 255) | ((a.y & 255) << 8) | ((a.z & 255) << 16) | (a.w << 24);
    o.y = (b.x & 255) | ((b.y & 255) << 8) | ((b.z & 255) << 16) | (b.w << 24);
    o.z = (c.x & 255) | ((c.y & 255) << 8) | ((c.z & 255) << 16) | (c.w << 24);
    o.w = (d.x & 255) | ((d.y & 255) << 8) | ((d.z & 255) << 16) | (d.w << 24);
    ((int4*)dst)[i] = o;
  }
}

// Duplicate first half of d_out into second half (int4). Fallback path only.
__global__ void dup_out(const int* __restrict__ src, int* __restrict__ dst, int n4){
  int stride = gridDim.x * blockDim.x;
  for (int i = blockIdx.x * blockDim.x + threadIdx.x; i < n4; i += stride)
    ((int4*)dst)[i] = ((const int4*)src)[i];
}

// Dual-GEMM 128x128 tile, double-buffered LDS (2x32KB), 2-phase prefetch,
// XCD-chunked block swizzle. acc1 = A1@B1^T, acc2 = A2@B2^T (B row-major
// (out,in) -> K-contiguous). i8 MFMA 16x16x64.
// PHASE 1: f_t = clip(clip(acc1//720)+clip(acc2//720)+bias); fg = f_t+127
//          fbuf[idx] = fg (int32); g8out[idx] = clip((fg*state)>>8)
// PHASE 2: h = clip(...); ns = clip(st + ((fbuf[idx]*(h-st))>>8));
//          fbuf[idx] = ns; if(out2) out2[idx] = ns
template<int PHASE>
__global__ __launch_bounds__(256, 2)
void gemm_dual(const int8_t* __restrict__ A1, const int8_t* __restrict__ A2,
               const int8_t* __restrict__ B1, const int8_t* __restrict__ B2,
               const int* __restrict__ bias,
               const int8_t* __restrict__ state8,
               int* fbuf, int8_t* __restrict__ g8out, int* __restrict__ out2)
{
  __shared__ __align__(16) int8_t lds[2 * 32768];   // dbuf x (A1,A2,B1,B2 x 8KB)
  const int tid  = threadIdx.x;
  const int lane = tid & 63;
  const int wave = tid >> 6;
  const int wrow = wave >> 1, wcol = wave & 1;

  // XCD-chunked bijective swizzle: 2048 blocks = 8 XCDs x 256-chunk.
  // Within a chunk colbase varies fast -> resident blocks share A row-panels.
  const int bid = blockIdx.x;
  const int wg  = (bid & 7) * 256 + (bid >> 3);
  const int rowbase = (wg >> 4) * 128;
  const int colbase = (wg & 15) * 128;

  v4i accA[4][4], accB[4][4];
  const v4i vzero = {0, 0, 0, 0};
#pragma unroll
  for (int m = 0; m < 4; m++)
#pragma unroll
    for (int n = 0; n < 4; n++){ accA[m][n] = vzero; accB[m][n] = vzero; }

  const int srow   = tid >> 2;   // 0..63 staging row within 64-row pass
  const int schunk = tid & 3;    // 16B chunk within 64B row
  const int chunk  = lane >> 4;  // frag-read 16B chunk
  const int rl     = lane & 15;

  // stage the 4 tiles' K-slice kk into buffer buf (linear LDS dest,
  // inverse-swizzled global source)
  auto STAGE = [&](int buf, int kk){
    const int k0 = kk * 64;
    const int bb = buf * 32768;
#pragma unroll
    for (int p = 0; p < 2; p++){
      const int row = p * 64 + srow;
      const int swc = schunk ^ ((row >> 1) & 3);
      const size_t aoff = (size_t)(rowbase + row) * HH + k0 + swc * 16;
      const size_t boff = (size_t)(colbase + row) * HH + k0 + swc * 16;
      const int ldst = bb + p * 4096 + tid * 16;
      __builtin_amdgcn_global_load_lds((const __attribute__((address_space(1))) void*)(A1 + aoff),
                                       (__attribute__((address_space(3))) void*)(lds + ldst), 16, 0, 0);
      __builtin_amdgcn_global_load_lds((const __attribute__((address_space(1))) void*)(A2 + aoff),
                                       (__attribute__((address_space(3))) void*)(lds + 8192 + ldst), 16, 0, 0);
      __builtin_amdgcn_global_load_lds((const __attribute__((address_space(1))) void*)(B1 + boff),
                                       (__attribute__((address_space(3))) void*)(lds + 16384 + ldst), 16, 0, 0);
      __builtin_amdgcn_global_load_lds((const __attribute__((address_space(1))) void*)(B2 + boff),
                                       (__attribute__((address_space(3))) void*)(lds + 24576 + ldst), 16, 0, 0);
    }
  };

  int cur = 0;
  STAGE(0, 0);
  __syncthreads();

  for (int kk = 0; kk < NK; ++kk){
    if (kk + 1 < NK) STAGE(cur ^ 1, kk + 1);   // prefetch next slice over MFMA
    const int cb = cur * 32768;
    // pair 1: A1 x B1
    {
      v4i af[4], bf[4];
#pragma unroll
      for (int m = 0; m < 4; m++){
        const int row = wrow * 64 + m * 16 + rl;
        af[m] = *(const v4i*)(lds + cb + row * 64 + ((chunk ^ ((row >> 1) & 3)) << 4));
      }
#pragma unroll
      for (int n = 0; n < 4; n++){
        const int row = wcol * 64 + n * 16 + rl;
        bf[n] = *(const v4i*)(lds + cb + 16384 + row * 64 + ((chunk ^ ((row >> 1) & 3)) << 4));
      }
#pragma unroll
      for (int m = 0; m < 4; m++)
#pragma unroll
        for (int n = 0; n < 4; n++)
          accA[m][n] = __builtin_amdgcn_mfma_i32_16x16x64_i8(af[m], bf[n], accA[m][n], 0, 0, 0);
    }
    // pair 2: A2 x B2
    {
      v4i af[4], bf[4];
#pragma unroll
      for (int m = 0; m < 4; m++){
        const int row = wrow * 64 + m * 16 + rl;
        af[m] = *(const v4i*)(lds + cb + 8192 + row * 64 + ((chunk ^ ((row >> 1) & 3)) << 4));
      }
#pragma unroll
      for (int n = 0; n < 4; n++){
        const int row = wcol * 64 + n * 16 + rl;
        bf[n] = *(const v4i*)(lds + cb + 24576 + row * 64 + ((chunk ^ ((row >> 1) & 3)) << 4));
      }
#pragma unroll
      for (int m = 0; m < 4; m++)
#pragma unroll
        for (int n = 0; n < 4; n++)
          accB[m][n] = __builtin_amdgcn_mfma_i32_16x16x64_i8(af[m], bf[n], accB[m][n], 0, 0, 0);
    }
    __syncthreads();   // prefetch landed + all reads of cur done
    cur ^= 1;
  }

  // epilogue: C/D layout col=lane&15, row=(lane>>4)*4+reg
  const int q = lane >> 4;
#pragma unroll
  for (int m = 0; m < 4; m++){
#pragma unroll
    for (int n = 0; n < 4; n++){
      const int gcol = colbase + wcol * 64 + n * 16 + rl;
      const int bval = bias[gcol];
#pragma unroll
      for (int r = 0; r < 4; r++){
        const int grow = rowbase + wrow * 64 + m * 16 + q * 4 + r;
        const size_t idx = (size_t)grow * HH + gcol;
        const int v1 = clip127(fdiv720(accA[m][n][r]));
        const int v2 = clip127(fdiv720(accB[m][n][r]));
        const int t  = clip127(v1 + v2 + bval);   // f_t or h_tilde
        const int st = state8[idx];
        if (PHASE == 1){
          const int fg = t + 127;
          fbuf[idx]  = fg;                          // int32, d_out first half
          g8out[idx] = (int8_t)clip127((fg * st) >> 8);
        } else {
          const int fg = fbuf[idx];
          const int ns = clip127(st + ((fg * (t - st)) >> 8));
          fbuf[idx] = ns;                           // output 0 (same-thread r/w)
          if (out2) out2[idx] = ns;                 // output 1 (ws path)
        }
      }
    }
  }
}

extern "C" void kernel_launch(void* const* d_in, const int* in_sizes, int n_in,
                              void* d_out, int out_size, void* d_ws, size_t ws_size,
                              hipStream_t stream){
  const int* x  = (const int*)d_in[0];
  const int* st = (const int*)d_in[1];
  const int* Wf = (const int*)d_in[2];
  const int* Uf = (const int*)d_in[3];
  const int* bf = (const int*)d_in[4];
  const int* Wh = (const int*)d_in[5];
  const int* Uh = (const int*)d_in[6];
  const int* bh = (const int*)d_in[7];

  const size_t NBH = (size_t)BB * HH;   // 33,554,432 elements
  const size_t NW  = (size_t)HH * HH;   //  4,194,304 elements
  const size_t need = 3 * NBH + 4 * NW; // 112 MiB of int8 scratch

  // d_out: int32 x 2*NBH (tuple). First half carries fg (int32) then new_state.
  // Scratch (x8|s8|g8|4 weights) goes to d_ws if large enough; else to d_out's
  // second half (then dup_out fills output 1 at the end).
  int*    out1   = (int*)d_out;
  const bool wsp = (ws_size >= need);
  int8_t* base   = wsp ? (int8_t*)d_ws : (int8_t*)d_out + NBH * 4;
  int8_t* x8  = base;
  int8_t* s8  = x8 + NBH;
  int8_t* g8  = s8 + NBH;
  int8_t* wf8 = g8 + NBH;
  int8_t* uf8 = wf8 + NW;
  int8_t* wh8 = uf8 + NW;
  int8_t* uh8 = wh8 + NW;

  pack_i32_to_i8<<<2048, 256, 0, stream>>>(x,  x8,  (int)(NBH / 16));
  pack_i32_to_i8<<<2048, 256, 0, stream>>>(st, s8,  (int)(NBH / 16));
  pack_i32_to_i8<<<1024, 256, 0, stream>>>(Wf, wf8, (int)(NW / 16));
  pack_i32_to_i8<<<1024, 256, 0, stream>>>(Uf, uf8, (int)(NW / 16));
  pack_i32_to_i8<<<1024, 256, 0, stream>>>(Wh, wh8, (int)(NW / 16));
  pack_i32_to_i8<<<1024, 256, 0, stream>>>(Uh, uh8, (int)(NW / 16));

  // grid: (16384/128) x (2048/128) = 2048 blocks of 256 threads
  gemm_dual<1><<<2048, 256, 0, stream>>>(x8, s8, wf8, uf8, bf, s8, out1, g8, nullptr);
  gemm_dual<2><<<2048, 256, 0, stream>>>(x8, g8, wh8, uh8, bh, s8, out1, nullptr,
                                         wsp ? out1 + NBH : nullptr);

  if (!wsp)
    dup_out<<<2048, 256, 0, stream>>>(out1, out1 + NBH, (int)(NBH / 4));
}